// Round 14
// baseline (299.789 us; speedup 1.0000x reference)
//
#include <hip/hip_runtime.h>
#include <hip/hip_bf16.h>

#define N_NODES_C 100000
#define N_EDGES_C 150000
#define DC 512
#define NG 64

typedef float f32x4 __attribute__((ext_vector_type(4)));
typedef short s16x8 __attribute__((ext_vector_type(8)));
typedef unsigned int u32;

__device__ __forceinline__ short f2bf(float f) {
    union { float f; unsigned u; } c; c.f = f;
    unsigned r = c.u + 0x7fffu + ((c.u >> 16) & 1u);
    return (short)(r >> 16);
}
__device__ __forceinline__ float bf2f(short v) {
    union { unsigned u; float f; } c;
    c.u = ((unsigned)(unsigned short)v) << 16;
    return c.f;
}

// async global->LDS, 16B per lane; LDS dest is wave-uniform base + lane*16
__device__ __forceinline__ void gload16(const void* g, void* l) {
    __builtin_amdgcn_global_load_lds((const __attribute__((address_space(1))) u32*)g,
                                     (__attribute__((address_space(3))) u32*)l,
                                     16, 0, 0);
}

// ---------------- small kernels ----------------

__global__ void zero_k(float* s, float* aggs, int* cnt, float* gsum, float* gcnt) {
    int i = blockIdx.x * 256 + threadIdx.x;
    if (i < N_NODES_C) { s[i] = 0.f; aggs[i] = 0.f; cnt[i] = 0; }
    if (i < NG) { gsum[i] = 0.f; gcnt[i] = 0.f; }
}

// out[n][k] = bf16(in[k][n]); both weights in one launch (blockIdx.z selects)
__global__ void transpose_w2(const float* __restrict__ in0, const float* __restrict__ in1,
                             short* __restrict__ out0, short* __restrict__ out1) {
    __shared__ float tile[32][33];
    const float* in = blockIdx.z ? in1 : in0;
    short* out = blockIdx.z ? out1 : out0;
    int tx = threadIdx.x & 31;
    int ty = threadIdx.x >> 5;  // 0..7
    int k0 = blockIdx.y * 32;
    int n0 = blockIdx.x * 32;
#pragma unroll
    for (int i = 0; i < 4; ++i)
        tile[ty + i * 8][tx] = in[(size_t)(k0 + ty + i * 8) * DC + n0 + tx];
    __syncthreads();
#pragma unroll
    for (int i = 0; i < 4; ++i)
        out[(size_t)(n0 + ty + i * 8) * DC + k0 + tx] = f2bf(tile[tx][ty + i * 8]);
}

// ---------------- counting sort of edges by dst ----------------

__global__ void hist_k(const int* __restrict__ ei, int* __restrict__ cnt) {
    int e = blockIdx.x * 256 + threadIdx.x;
    if (e < N_EDGES_C) atomicAdd(&cnt[ei[N_EDGES_C + e]], 1);
}

__global__ void scan1_k(const int* __restrict__ cnt, int* __restrict__ off,
                        int* __restrict__ bsum) {
    __shared__ int sh[1024];
    int tid = threadIdx.x;
    int i = blockIdx.x * 1024 + tid;
    int v = (i < N_NODES_C) ? cnt[i] : 0;
    sh[tid] = v;
    __syncthreads();
    for (int d = 1; d < 1024; d <<= 1) {
        int t = (tid >= d) ? sh[tid - d] : 0;
        __syncthreads();
        sh[tid] += t;
        __syncthreads();
    }
    if (i < N_NODES_C) off[i] = sh[tid] - v;  // exclusive
    if (tid == 1023) bsum[blockIdx.x] = sh[1023];
}

#define NSCAN_BLK 98  // ceil(100000/1024)

__global__ void scan2_k(int* __restrict__ bsum) {
    __shared__ int sh[128];
    int tid = threadIdx.x;
    int v = (tid < NSCAN_BLK) ? bsum[tid] : 0;
    sh[tid] = v;
    __syncthreads();
    for (int d = 1; d < 128; d <<= 1) {
        int t = (tid >= d) ? sh[tid - d] : 0;
        __syncthreads();
        sh[tid] += t;
        __syncthreads();
    }
    if (tid < NSCAN_BLK) bsum[tid] = sh[tid] - v;  // exclusive
}

__global__ void scan3_k(int* __restrict__ off, const int* __restrict__ bsum) {
    int i = blockIdx.x * 1024 + threadIdx.x;
    if (i < N_NODES_C) off[i] += bsum[blockIdx.x];
}

// place: off becomes end-cursor; after completion off[i] = start of node i+1
__global__ void place_k(const int* __restrict__ ei, int* __restrict__ off,
                        int* __restrict__ ssrc) {
    int e = blockIdx.x * 256 + threadIdx.x;
    if (e < N_EDGES_C) {
        int d = ei[N_EDGES_C + e];
        int p = atomicAdd(&off[d], 1);
        ssrc[p] = ei[e];
    }
}

// z1[i] = bf16(relu(y[i] + sum_{e:dst=i} y[src_e] + b1a)); 4 nodes/block, 64 lanes/node
__global__ void gather_relu_k(const short* __restrict__ y, const int* __restrict__ off,
                              const int* __restrict__ ssrc, const float* __restrict__ b1a,
                              short* __restrict__ z1) {
    int node = blockIdx.x * 4 + (threadIdx.x >> 6);
    if (node >= N_NODES_C) return;
    int t = threadIdx.x & 63;
    const int col = t * 8;
    int beg = (node == 0) ? 0 : off[node - 1];
    int end = off[node];
    s16x8 own = *(const s16x8*)(y + (size_t)node * DC + col);
    float acc[8];
#pragma unroll
    for (int q = 0; q < 8; ++q) acc[q] = bf2f(own[q]);
    int j = beg;
    for (; j + 2 <= end; j += 2) {
        int s0 = ssrc[j];
        int s1 = ssrc[j + 1];
        s16x8 r0 = *(const s16x8*)(y + (size_t)s0 * DC + col);
        s16x8 r1 = *(const s16x8*)(y + (size_t)s1 * DC + col);
#pragma unroll
        for (int q = 0; q < 8; ++q) acc[q] += bf2f(r0[q]) + bf2f(r1[q]);
    }
    if (j < end) {
        int s0 = ssrc[j];
        s16x8 r0 = *(const s16x8*)(y + (size_t)s0 * DC + col);
#pragma unroll
        for (int q = 0; q < 8; ++q) acc[q] += bf2f(r0[q]);
    }
    f32x4 bv0 = *(const f32x4*)(b1a + col);
    f32x4 bv1 = *(const f32x4*)(b1a + col + 4);
    s16x8 o;
    o[0] = f2bf(fmaxf(acc[0] + bv0.x, 0.f));
    o[1] = f2bf(fmaxf(acc[1] + bv0.y, 0.f));
    o[2] = f2bf(fmaxf(acc[2] + bv0.z, 0.f));
    o[3] = f2bf(fmaxf(acc[3] + bv0.w, 0.f));
    o[4] = f2bf(fmaxf(acc[4] + bv1.x, 0.f));
    o[5] = f2bf(fmaxf(acc[5] + bv1.y, 0.f));
    o[6] = f2bf(fmaxf(acc[6] + bv1.z, 0.f));
    o[7] = f2bf(fmaxf(acc[7] + bv1.w, 0.f));
    *(s16x8*)(z1 + (size_t)node * DC + col) = o;
}

// ---------------- scalar tail ----------------

__global__ void edge_scalar(const int* __restrict__ ei, const float* __restrict__ s,
                            float* __restrict__ aggs) {
    int e = blockIdx.x * 256 + threadIdx.x;
    if (e < N_EDGES_C) atomicAdd(&aggs[ei[N_EDGES_C + e]], s[ei[e]]);
}

__global__ void node_pool(const float* __restrict__ s, const float* __restrict__ aggs,
                          const int* __restrict__ batch, const float* __restrict__ b2a,
                          float* __restrict__ gsum, float* __restrict__ gcnt) {
    __shared__ float ls[NG], lc[NG];
    int t = threadIdx.x;
    if (t < NG) { ls[t] = 0.f; lc[t] = 0.f; }
    __syncthreads();
    int i = blockIdx.x * 256 + t;
    if (i < N_NODES_C) {
        float z2 = fmaxf(aggs[i] + s[i] + b2a[0], 0.0f);
        int g = batch[i];
        atomicAdd(&ls[g], z2);
        atomicAdd(&lc[g], 1.0f);
    }
    __syncthreads();
    if (t < NG && lc[t] != 0.f) {
        atomicAdd(&gsum[t], ls[t]);
        atomicAdd(&gcnt[t], lc[t]);
    }
}

__global__ void finalize_k(const float* gsum, const float* gcnt, const float* w2b,
                           const float* b2b, float* out) {
    int g = threadIdx.x;
    if (g < NG) {
        float c = fmaxf(gcnt[g], 1.0f);
        out[g] = gsum[g] / c * w2b[0] + b2b[0];
    }
}

// ---------------- GEMM0 (round-12 proven: 128x128, BK=32, f32 A fused cvt) --
#define BM 128
#define BN 128
#define BK 32
#define NKT (DC / BK)  // 16
#define NWG 3128       // 782 row tiles * 4 col tiles = 8 * 391
#define WPX 391

__global__ __launch_bounds__(256, 3) void gemm0_k(const float* __restrict__ Ap,
                                                  const short* __restrict__ Bt,
                                                  short* __restrict__ Cout) {
    __shared__ alignas(16) short As[BM * BK];  // 8 KB
    __shared__ alignas(16) short Bs[BN * BK];  // 8 KB

    const int tid = threadIdx.x;
    const int bid = blockIdx.x;
    const int lin = (bid & 7) * WPX + (bid >> 3);
    const int brow = (lin >> 2) * BM;
    const int bcol = (lin & 3) * BN;

    const int w    = tid >> 6;
    const int lane = tid & 63;
    const int wr   = (w >> 1) * 64;
    const int wc   = (w & 1) * 64;
    const int lr   = lane & 15;
    const int lg   = lane >> 4;
    const int lswz = (lr >> 1) & 3;

    f32x4 acc[4][4] = {};

    const int srow = lane >> 2;
    const int scol = (((lane & 3) ^ ((srow >> 1) & 3)) * 8);

    const short* bg0 = Bt + (size_t)(bcol + w * 32 + srow) * DC + scol;
    const short* bg1 = bg0 + (size_t)16 * DC;
    short* bl0 = &Bs[(w * 32) * BK];
    short* bl1 = &Bs[(w * 32 + 16) * BK];

    const int rAl = tid >> 1;
    int r = brow + rAl;
    if (r >= N_NODES_C) r = N_NODES_C - 1;
    const float* axsrc = Ap + (size_t)r * DC + (tid & 1) * 16;
    const int rswz = (rAl >> 1) & 3;
    const int awoff0 = rAl * BK + ((((tid & 1) * 2 + 0) ^ rswz) * 8);
    const int awoff1 = rAl * BK + ((((tid & 1) * 2 + 1) ^ rswz) * 8);

    f32x4 areg[4];
#pragma unroll
    for (int q = 0; q < 4; ++q) areg[q] = *(const f32x4*)(axsrc + q * 4);

    for (int kt = 0; kt < NKT; ++kt) {
        const int k0 = kt * BK;
        __syncthreads();
        s16x8 c0, c1;
        c0[0] = f2bf(areg[0].x); c0[1] = f2bf(areg[0].y);
        c0[2] = f2bf(areg[0].z); c0[3] = f2bf(areg[0].w);
        c0[4] = f2bf(areg[1].x); c0[5] = f2bf(areg[1].y);
        c0[6] = f2bf(areg[1].z); c0[7] = f2bf(areg[1].w);
        c1[0] = f2bf(areg[2].x); c1[1] = f2bf(areg[2].y);
        c1[2] = f2bf(areg[2].z); c1[3] = f2bf(areg[2].w);
        c1[4] = f2bf(areg[3].x); c1[5] = f2bf(areg[3].y);
        c1[6] = f2bf(areg[3].z); c1[7] = f2bf(areg[3].w);
        *(s16x8*)&As[awoff0] = c0;
        *(s16x8*)&As[awoff1] = c1;
        gload16(bg0 + k0, bl0);
        gload16(bg1 + k0, bl1);
        __syncthreads();

        if (kt + 1 < NKT) {
#pragma unroll
            for (int q = 0; q < 4; ++q)
                areg[q] = *(const f32x4*)(axsrc + (kt + 1) * BK + q * 4);
        }

        s16x8 af[4], bfr[4];
#pragma unroll
        for (int mi = 0; mi < 4; ++mi)
            af[mi] = *(const s16x8*)&As[(wr + mi * 16 + lr) * BK + ((lg ^ lswz) * 8)];
#pragma unroll
        for (int ni = 0; ni < 4; ++ni)
            bfr[ni] = *(const s16x8*)&Bs[(wc + ni * 16 + lr) * BK + ((lg ^ lswz) * 8)];
        __builtin_amdgcn_s_setprio(1);
#pragma unroll
        for (int mi = 0; mi < 4; ++mi)
#pragma unroll
            for (int ni = 0; ni < 4; ++ni)
                acc[mi][ni] = __builtin_amdgcn_mfma_f32_16x16x32_bf16(af[mi], bfr[ni],
                                                                      acc[mi][ni], 0, 0, 0);
        __builtin_amdgcn_s_setprio(0);
    }

    const int rb = brow + wr + lg * 4;
    const int cb = bcol + wc + lr;
#pragma unroll
    for (int mi = 0; mi < 4; ++mi) {
#pragma unroll
        for (int rr = 0; rr < 4; ++rr) {
            int row = rb + mi * 16 + rr;
            if (row < N_NODES_C) {
#pragma unroll
                for (int ni = 0; ni < 4; ++ni)
                    Cout[(size_t)row * DC + cb + ni * 16] = f2bf(acc[mi][ni][rr]);
            }
        }
    }
}

// ---------------- GEMM1: 256x128 tile, 8 waves, BK=32 ----------------
// 1.33x MFMA per staged byte, 2x MFMA per barrier vs 128^2. Per-wave acc
// stays 4x4 (64 AGPR + ~60 arch VGPR -> ~2 blocks/CU). Same verified
// XOR swizzle. h = relu(A@W + bias); s_out[row] += h . w2a (no C matrix).
#define G2_BM 256
#define G2_NWG 1564  // 391 row tiles * 4 col tiles (not /8 -> m204 remap)

__global__ __launch_bounds__(512, 2) void gemm1_k(const short* __restrict__ A,
                                                  const short* __restrict__ Bt,
                                                  const float* __restrict__ bias,
                                                  const float* __restrict__ w2a,
                                                  float* __restrict__ s_out) {
    __shared__ alignas(16) short As[G2_BM * BK];  // 16 KB
    __shared__ alignas(16) short Bs[BN * BK];     // 8 KB

    const int tid = threadIdx.x;
    // m204 bijective XCD remap for 1564 = 8*195 + 4
    const int bid = blockIdx.x;
    const int q = G2_NWG / 8, rr8 = G2_NWG % 8;
    const int xcd = bid & 7;
    const int lin = (xcd < rr8 ? xcd * (q + 1) : rr8 * (q + 1) + (xcd - rr8) * q) + (bid >> 3);
    const int brow = (lin >> 2) * G2_BM;
    const int bcol = (lin & 3) * BN;

    const int w    = tid >> 6;       // wave 0..7
    const int lane = tid & 63;
    const int wm   = w >> 1;         // 0..3: 64-row band
    const int wn   = w & 1;          // 0..1: 64-col half
    const int lr   = lane & 15;
    const int lg   = lane >> 4;
    const int lswz = (lr >> 1) & 3;

    f32x4 acc[4][4] = {};

    const int srow = lane >> 2;  // 0..15
    const int scol = (((lane & 3) ^ ((srow >> 1) & 3)) * 8);

    // A: wave w stages rows w*32+srow and +16 (covers 256 rows over 8 waves)
    int ar0 = brow + w * 32 + srow;
    int ar1 = ar0 + 16;
    if (ar0 >= N_NODES_C) ar0 = N_NODES_C - 1;
    if (ar1 >= N_NODES_C) ar1 = N_NODES_C - 1;
    const short* ag0 = A + (size_t)ar0 * DC + scol;
    const short* ag1 = A + (size_t)ar1 * DC + scol;
    short* al0 = &As[(w * 32) * BK];
    short* al1 = &As[(w * 32 + 16) * BK];
    // B: wave w stages rows w*16+srow (covers 128 rows over 8 waves)
    const short* bg = Bt + (size_t)(bcol + w * 16 + srow) * DC + scol;
    short* bl = &Bs[(w * 16) * BK];

    for (int kt = 0; kt < NKT; ++kt) {
        const int k0 = kt * BK;
        __syncthreads();
        gload16(ag0 + k0, al0);
        gload16(ag1 + k0, al1);
        gload16(bg + k0, bl);
        __syncthreads();

        s16x8 af[4], bfr[4];
#pragma unroll
        for (int mi = 0; mi < 4; ++mi)
            af[mi] = *(const s16x8*)&As[(wm * 64 + mi * 16 + lr) * BK + ((lg ^ lswz) * 8)];
#pragma unroll
        for (int ni = 0; ni < 4; ++ni)
            bfr[ni] = *(const s16x8*)&Bs[(wn * 64 + ni * 16 + lr) * BK + ((lg ^ lswz) * 8)];
        __builtin_amdgcn_s_setprio(1);
#pragma unroll
        for (int mi = 0; mi < 4; ++mi)
#pragma unroll
            for (int ni = 0; ni < 4; ++ni)
                acc[mi][ni] = __builtin_amdgcn_mfma_f32_16x16x32_bf16(af[mi], bfr[ni],
                                                                      acc[mi][ni], 0, 0, 0);
        __builtin_amdgcn_s_setprio(0);
    }

    // C/D layout: col = lane&15, row = (lane>>4)*4 + reg
    const int rb = brow + wm * 64 + lg * 4;
    const int cb = bcol + wn * 64 + lr;

    float bv[4], wv[4];
#pragma unroll
    for (int ni = 0; ni < 4; ++ni) {
        bv[ni] = bias[cb + ni * 16];
        wv[ni] = w2a[cb + ni * 16];
    }
#pragma unroll
    for (int mi = 0; mi < 4; ++mi) {
#pragma unroll
        for (int rr = 0; rr < 4; ++rr) {
            float sum = 0.f;
#pragma unroll
            for (int ni = 0; ni < 4; ++ni) {
                float v = fmaxf(acc[mi][ni][rr] + bv[ni], 0.0f);
                sum += v * wv[ni];
            }
#pragma unroll
            for (int off = 1; off < 16; off <<= 1) sum += __shfl_xor(sum, off, 64);
            int row = rb + mi * 16 + rr;
            if (lr == 0 && row < N_NODES_C) atomicAdd(&s_out[row], sum);
        }
    }
}

// ---------------- launch ----------------

extern "C" void kernel_launch(void* const* d_in, const int* in_sizes, int n_in,
                              void* d_out, int out_size, void* d_ws, size_t ws_size,
                              hipStream_t stream) {
    const float* x     = (const float*)d_in[0];
    const int*   ei    = (const int*)d_in[1];
    const int*   batch = (const int*)d_in[2];
    const float* W1a   = (const float*)d_in[3];
    const float* b1a   = (const float*)d_in[4];
    const float* W1b   = (const float*)d_in[5];
    const float* b1b   = (const float*)d_in[6];
    const float* W2a   = (const float*)d_in[7];
    const float* b2a   = (const float*)d_in[8];
    const float* W2b   = (const float*)d_in[9];
    const float* b2b   = (const float*)d_in[10];
    float* out = (float*)d_out;

    char* w = (char*)d_ws;
    short* z1   = (short*)(w);                  // 102,400,000
    short* y    = (short*)(w + 102400000);      // 102,400,000
    short* WT1  = (short*)(w + 204800000);      // 524,288
    short* WT2  = (short*)(w + 205324288);      // 524,288
    float* sbuf = (float*)(w + 205848576);      // 400,000
    float* aggs = (float*)(w + 206248576);      // 400,000
    int*   cnt  = (int*)  (w + 206648576);      // 400,000
    int*   offb = (int*)  (w + 207048576);      // 400,000
    int*   ssrc = (int*)  (w + 207448576);      // 600,000
    int*   bsum = (int*)  (w + 208048576);      // 512
    float* gsum = (float*)(w + 208049088);      // 256
    float* gcnt = (float*)(w + 208049344);      // 256

    zero_k<<<391, 256, 0, stream>>>(sbuf, aggs, cnt, gsum, gcnt);
    transpose_w2<<<dim3(16, 16, 2), 256, 0, stream>>>(W1a, W1b, WT1, WT2);

    // CSR build (independent of GEMM0)
    hist_k<<<586, 256, 0, stream>>>(ei, cnt);
    scan1_k<<<NSCAN_BLK, 1024, 0, stream>>>(cnt, offb, bsum);
    scan2_k<<<1, 128, 0, stream>>>(bsum);
    scan3_k<<<NSCAN_BLK, 1024, 0, stream>>>(offb, bsum);
    place_k<<<586, 256, 0, stream>>>(ei, offb, ssrc);

    // y = bf16(x) @ W1a  (f32 A, fused convert in staging)
    gemm0_k<<<NWG, 256, 0, stream>>>(x, WT1, y);
    // z1 = relu(y + agg(y) + b1a)
    gather_relu_k<<<25000, 256, 0, stream>>>(y, offb, ssrc, b1a, z1);
    // s = relu(z1 @ W1b + b1b) . W2a
    gemm1_k<<<G2_NWG, 512, 0, stream>>>(z1, WT2, b1b, W2a, sbuf);

    edge_scalar<<<586, 256, 0, stream>>>(ei, sbuf, aggs);
    node_pool<<<391, 256, 0, stream>>>(sbuf, aggs, batch, b2a, gsum, gcnt);
    finalize_k<<<1, 64, 0, stream>>>(gsum, gcnt, W2b, b2b, out);
}

// Round 15
// 299.259 us; speedup vs baseline: 1.0018x; 1.0018x over previous
//
#include <hip/hip_runtime.h>
#include <hip/hip_bf16.h>

#define N_NODES_C 100000
#define N_EDGES_C 150000
#define DC 512
#define NG 64

typedef float f32x4 __attribute__((ext_vector_type(4)));
typedef short s16x8 __attribute__((ext_vector_type(8)));
typedef unsigned int u32;

__device__ __forceinline__ short f2bf(float f) {
    union { float f; unsigned u; } c; c.f = f;
    unsigned r = c.u + 0x7fffu + ((c.u >> 16) & 1u);
    return (short)(r >> 16);
}
__device__ __forceinline__ float bf2f(short v) {
    union { unsigned u; float f; } c;
    c.u = ((unsigned)(unsigned short)v) << 16;
    return c.f;
}

// async global->LDS, 16B per lane; LDS dest is wave-uniform base + lane*16
__device__ __forceinline__ void gload16(const void* g, void* l) {
    __builtin_amdgcn_global_load_lds((const __attribute__((address_space(1))) u32*)g,
                                     (__attribute__((address_space(3))) u32*)l,
                                     16, 0, 0);
}

// ---------------- small kernels ----------------

// out[n][k] = bf16(in[k][n]); both weights in one launch (blockIdx.z selects)
__global__ void transpose_w2(const float* __restrict__ in0, const float* __restrict__ in1,
                             short* __restrict__ out0, short* __restrict__ out1) {
    __shared__ float tile[32][33];
    const float* in = blockIdx.z ? in1 : in0;
    short* out = blockIdx.z ? out1 : out0;
    int tx = threadIdx.x & 31;
    int ty = threadIdx.x >> 5;  // 0..7
    int k0 = blockIdx.y * 32;
    int n0 = blockIdx.x * 32;
#pragma unroll
    for (int i = 0; i < 4; ++i)
        tile[ty + i * 8][tx] = in[(size_t)(k0 + ty + i * 8) * DC + n0 + tx];
    __syncthreads();
#pragma unroll
    for (int i = 0; i < 4; ++i)
        out[(size_t)(n0 + ty + i * 8) * DC + k0 + tx] = f2bf(tile[tx][ty + i * 8]);
}

// ---------------- counting sort of edges by dst ----------------

__global__ void hist_k(const int* __restrict__ ei, int* __restrict__ cnt) {
    int e = blockIdx.x * 256 + threadIdx.x;
    if (e < N_EDGES_C) atomicAdd(&cnt[ei[N_EDGES_C + e]], 1);
}

__global__ void scan1_k(const int* __restrict__ cnt, int* __restrict__ off,
                        int* __restrict__ bsum) {
    __shared__ int sh[1024];
    int tid = threadIdx.x;
    int i = blockIdx.x * 1024 + tid;
    int v = (i < N_NODES_C) ? cnt[i] : 0;
    sh[tid] = v;
    __syncthreads();
    for (int d = 1; d < 1024; d <<= 1) {
        int t = (tid >= d) ? sh[tid - d] : 0;
        __syncthreads();
        sh[tid] += t;
        __syncthreads();
    }
    if (i < N_NODES_C) off[i] = sh[tid] - v;  // exclusive
    if (tid == 1023) bsum[blockIdx.x] = sh[1023];
}

#define NSCAN_BLK 98  // ceil(100000/1024)

__global__ void scan2_k(int* __restrict__ bsum) {
    __shared__ int sh[128];
    int tid = threadIdx.x;
    int v = (tid < NSCAN_BLK) ? bsum[tid] : 0;
    sh[tid] = v;
    __syncthreads();
    for (int d = 1; d < 128; d <<= 1) {
        int t = (tid >= d) ? sh[tid - d] : 0;
        __syncthreads();
        sh[tid] += t;
        __syncthreads();
    }
    if (tid < NSCAN_BLK) bsum[tid] = sh[tid] - v;  // exclusive
}

__global__ void scan3_k(int* __restrict__ off, const int* __restrict__ bsum) {
    int i = blockIdx.x * 1024 + threadIdx.x;
    if (i < N_NODES_C) off[i] += bsum[blockIdx.x];
}

// place: off becomes end-cursor; after completion off[i] = start of node i+1
__global__ void place_k(const int* __restrict__ ei, int* __restrict__ off,
                        int* __restrict__ ssrc) {
    int e = blockIdx.x * 256 + threadIdx.x;
    if (e < N_EDGES_C) {
        int d = ei[N_EDGES_C + e];
        int p = atomicAdd(&off[d], 1);
        ssrc[p] = ei[e];
    }
}

// z1[i] = bf16(relu(y[i] + sum_{e:dst=i} y[src_e] + b1a)); 4 nodes/block, 64 lanes/node
__global__ void gather_relu_k(const short* __restrict__ y, const int* __restrict__ off,
                              const int* __restrict__ ssrc, const float* __restrict__ b1a,
                              short* __restrict__ z1) {
    int node = blockIdx.x * 4 + (threadIdx.x >> 6);
    if (node >= N_NODES_C) return;
    int t = threadIdx.x & 63;
    const int col = t * 8;
    int beg = (node == 0) ? 0 : off[node - 1];
    int end = off[node];
    s16x8 own = *(const s16x8*)(y + (size_t)node * DC + col);
    float acc[8];
#pragma unroll
    for (int q = 0; q < 8; ++q) acc[q] = bf2f(own[q]);
    int j = beg;
    for (; j + 2 <= end; j += 2) {
        int s0 = ssrc[j];
        int s1 = ssrc[j + 1];
        s16x8 r0 = *(const s16x8*)(y + (size_t)s0 * DC + col);
        s16x8 r1 = *(const s16x8*)(y + (size_t)s1 * DC + col);
#pragma unroll
        for (int q = 0; q < 8; ++q) acc[q] += bf2f(r0[q]) + bf2f(r1[q]);
    }
    if (j < end) {
        int s0 = ssrc[j];
        s16x8 r0 = *(const s16x8*)(y + (size_t)s0 * DC + col);
#pragma unroll
        for (int q = 0; q < 8; ++q) acc[q] += bf2f(r0[q]);
    }
    f32x4 bv0 = *(const f32x4*)(b1a + col);
    f32x4 bv1 = *(const f32x4*)(b1a + col + 4);
    s16x8 o;
    o[0] = f2bf(fmaxf(acc[0] + bv0.x, 0.f));
    o[1] = f2bf(fmaxf(acc[1] + bv0.y, 0.f));
    o[2] = f2bf(fmaxf(acc[2] + bv0.z, 0.f));
    o[3] = f2bf(fmaxf(acc[3] + bv0.w, 0.f));
    o[4] = f2bf(fmaxf(acc[4] + bv1.x, 0.f));
    o[5] = f2bf(fmaxf(acc[5] + bv1.y, 0.f));
    o[6] = f2bf(fmaxf(acc[6] + bv1.z, 0.f));
    o[7] = f2bf(fmaxf(acc[7] + bv1.w, 0.f));
    *(s16x8*)(z1 + (size_t)node * DC + col) = o;
}

// ---------------- scalar tail ----------------

__global__ void edge_scalar(const int* __restrict__ ei, const float* __restrict__ s,
                            float* __restrict__ aggs) {
    int e = blockIdx.x * 256 + threadIdx.x;
    if (e < N_EDGES_C) atomicAdd(&aggs[ei[N_EDGES_C + e]], s[ei[e]]);
}

__global__ void node_pool(const float* __restrict__ s, const float* __restrict__ aggs,
                          const int* __restrict__ batch, const float* __restrict__ b2a,
                          float* __restrict__ gsum, float* __restrict__ gcnt) {
    __shared__ float ls[NG], lc[NG];
    int t = threadIdx.x;
    if (t < NG) { ls[t] = 0.f; lc[t] = 0.f; }
    __syncthreads();
    int i = blockIdx.x * 256 + t;
    if (i < N_NODES_C) {
        float z2 = fmaxf(aggs[i] + s[i] + b2a[0], 0.0f);
        int g = batch[i];
        atomicAdd(&ls[g], z2);
        atomicAdd(&lc[g], 1.0f);
    }
    __syncthreads();
    if (t < NG && lc[t] != 0.f) {
        atomicAdd(&gsum[t], ls[t]);
        atomicAdd(&gcnt[t], lc[t]);
    }
}

__global__ void finalize_k(const float* gsum, const float* gcnt, const float* w2b,
                           const float* b2b, float* out) {
    int g = threadIdx.x;
    if (g < NG) {
        float c = fmaxf(gcnt[g], 1.0f);
        out[g] = gsum[g] / c * w2b[0] + b2b[0];
    }
}

// ---------------- GEMMs ----------------
// Round-12 config (best: 294 us) + ONE change: single-barrier double-buffered
// LDS. Per K-iter: stage(kt+1 -> buf^1) BEFORE compute(kt), then ONE
// __syncthreads (drains the stage, whose loads had the whole compute block to
// fly; closes the read window -> race-free WAR across iters). Halves barrier
// count (16 vs 32) and removes the drain-latency serialization of the 2-phase
// loop. Swizzle (verified 0-conflict), XCD remap, epilogues unchanged.
#define BM 128
#define BN 128
#define BK 32
#define NKT (DC / BK)  // 16
#define NWG 3128       // 782 row tiles * 4 col tiles = 8 * 391
#define WPX 391

// GEMM0: A f32, reg-staged fused f32->bf16 (areg loads at iter top, cvt+ds_write
// after MFMA — issue-early/write-late); B via gload_lds. C = A@W -> bf16.
__global__ __launch_bounds__(256, 3) void gemm0_k(const float* __restrict__ Ap,
                                                  const short* __restrict__ Bt,
                                                  short* __restrict__ Cout) {
    __shared__ alignas(16) short As[2][BM * BK];  // 2 x 8 KB
    __shared__ alignas(16) short Bs[2][BN * BK];  // 2 x 8 KB

    const int tid = threadIdx.x;
    const int bid = blockIdx.x;
    const int lin = (bid & 7) * WPX + (bid >> 3);
    const int brow = (lin >> 2) * BM;
    const int bcol = (lin & 3) * BN;

    const int w    = tid >> 6;
    const int lane = tid & 63;
    const int wr   = (w >> 1) * 64;
    const int wc   = (w & 1) * 64;
    const int lr   = lane & 15;
    const int lg   = lane >> 4;
    const int lswz = (lr >> 1) & 3;

    f32x4 acc[4][4] = {};

    const int srow = lane >> 2;
    const int scol = (((lane & 3) ^ ((srow >> 1) & 3)) * 8);

    const short* bg0 = Bt + (size_t)(bcol + w * 32 + srow) * DC + scol;
    const short* bg1 = bg0 + (size_t)16 * DC;

    const int rAl = tid >> 1;
    int r = brow + rAl;
    if (r >= N_NODES_C) r = N_NODES_C - 1;
    const float* axsrc = Ap + (size_t)r * DC + (tid & 1) * 16;
    const int rswz = (rAl >> 1) & 3;
    const int awoff0 = rAl * BK + ((((tid & 1) * 2 + 0) ^ rswz) * 8);
    const int awoff1 = rAl * BK + ((((tid & 1) * 2 + 1) ^ rswz) * 8);

    f32x4 areg[4];

#define CVT_WRITE_A(buf)                                         \
    do {                                                         \
        s16x8 c0, c1;                                            \
        c0[0] = f2bf(areg[0].x); c0[1] = f2bf(areg[0].y);        \
        c0[2] = f2bf(areg[0].z); c0[3] = f2bf(areg[0].w);        \
        c0[4] = f2bf(areg[1].x); c0[5] = f2bf(areg[1].y);        \
        c0[6] = f2bf(areg[1].z); c0[7] = f2bf(areg[1].w);        \
        c1[0] = f2bf(areg[2].x); c1[1] = f2bf(areg[2].y);        \
        c1[2] = f2bf(areg[2].z); c1[3] = f2bf(areg[2].w);        \
        c1[4] = f2bf(areg[3].x); c1[5] = f2bf(areg[3].y);        \
        c1[6] = f2bf(areg[3].z); c1[7] = f2bf(areg[3].w);        \
        *(s16x8*)&As[buf][awoff0] = c0;                          \
        *(s16x8*)&As[buf][awoff1] = c1;                          \
    } while (0)

    // prologue: tile 0 into buf 0
#pragma unroll
    for (int q = 0; q < 4; ++q) areg[q] = *(const f32x4*)(axsrc + q * 4);
    CVT_WRITE_A(0);
    gload16(bg0, &Bs[0][(w * 32) * BK]);
    gload16(bg1, &Bs[0][(w * 32 + 16) * BK]);
    __syncthreads();

    for (int kt = 0; kt < NKT; ++kt) {
        const int cur = kt & 1;
        if (kt + 1 < NKT) {
            const int k1 = (kt + 1) * BK;
#pragma unroll
            for (int q = 0; q < 4; ++q)
                areg[q] = *(const f32x4*)(axsrc + k1 + q * 4);
            gload16(bg0 + k1, &Bs[cur ^ 1][(w * 32) * BK]);
            gload16(bg1 + k1, &Bs[cur ^ 1][(w * 32 + 16) * BK]);
        }

        s16x8 af[4], bfr[4];
#pragma unroll
        for (int mi = 0; mi < 4; ++mi)
            af[mi] = *(const s16x8*)&As[cur][(wr + mi * 16 + lr) * BK + ((lg ^ lswz) * 8)];
#pragma unroll
        for (int ni = 0; ni < 4; ++ni)
            bfr[ni] = *(const s16x8*)&Bs[cur][(wc + ni * 16 + lr) * BK + ((lg ^ lswz) * 8)];
        __builtin_amdgcn_s_setprio(1);
#pragma unroll
        for (int mi = 0; mi < 4; ++mi)
#pragma unroll
            for (int ni = 0; ni < 4; ++ni)
                acc[mi][ni] = __builtin_amdgcn_mfma_f32_16x16x32_bf16(af[mi], bfr[ni],
                                                                      acc[mi][ni], 0, 0, 0);
        __builtin_amdgcn_s_setprio(0);

        if (kt + 1 < NKT) CVT_WRITE_A(cur ^ 1);  // waits areg loads (covered by MFMA)
        __syncthreads();  // one barrier: stage drained + read window closed
    }
#undef CVT_WRITE_A

    const int rb = brow + wr + lg * 4;
    const int cb = bcol + wc + lr;
#pragma unroll
    for (int mi = 0; mi < 4; ++mi) {
#pragma unroll
        for (int rr = 0; rr < 4; ++rr) {
            int row = rb + mi * 16 + rr;
            if (row < N_NODES_C) {
#pragma unroll
                for (int ni = 0; ni < 4; ++ni)
                    Cout[(size_t)row * DC + cb + ni * 16] = f2bf(acc[mi][ni][rr]);
            }
        }
    }
}

// GEMM1: A bf16 + B via gload_lds, same single-barrier dbuf.
// h = relu(A@W + bias); s_out[row] += h . w2a (no C matrix)
__global__ __launch_bounds__(256, 4) void gemm1_k(const short* __restrict__ A,
                                                  const short* __restrict__ Bt,
                                                  const float* __restrict__ bias,
                                                  const float* __restrict__ w2a,
                                                  float* __restrict__ s_out) {
    __shared__ alignas(16) short As[2][BM * BK];  // 2 x 8 KB
    __shared__ alignas(16) short Bs[2][BN * BK];  // 2 x 8 KB

    const int tid = threadIdx.x;
    const int bid = blockIdx.x;
    const int lin = (bid & 7) * WPX + (bid >> 3);
    const int brow = (lin >> 2) * BM;
    const int bcol = (lin & 3) * BN;

    const int w    = tid >> 6;
    const int lane = tid & 63;
    const int wr   = (w >> 1) * 64;
    const int wc   = (w & 1) * 64;
    const int lr   = lane & 15;
    const int lg   = lane >> 4;
    const int lswz = (lr >> 1) & 3;

    f32x4 acc[4][4] = {};

    const int srow = lane >> 2;
    const int scol = (((lane & 3) ^ ((srow >> 1) & 3)) * 8);

    int ar0 = brow + w * 32 + srow;
    int ar1 = ar0 + 16;
    if (ar0 >= N_NODES_C) ar0 = N_NODES_C - 1;  // clamp; stores guarded
    if (ar1 >= N_NODES_C) ar1 = N_NODES_C - 1;
    const short* ag0 = A + (size_t)ar0 * DC + scol;
    const short* ag1 = A + (size_t)ar1 * DC + scol;
    const short* bg0 = Bt + (size_t)(bcol + w * 32 + srow) * DC + scol;
    const short* bg1 = bg0 + (size_t)16 * DC;

#define STAGE1(k0, buf)                                  \
    do {                                                 \
        gload16(ag0 + (k0), &As[buf][(w * 32) * BK]);    \
        gload16(ag1 + (k0), &As[buf][(w * 32 + 16) * BK]); \
        gload16(bg0 + (k0), &Bs[buf][(w * 32) * BK]);    \
        gload16(bg1 + (k0), &Bs[buf][(w * 32 + 16) * BK]); \
    } while (0)

    STAGE1(0, 0);
    __syncthreads();

    for (int kt = 0; kt < NKT; ++kt) {
        const int cur = kt & 1;
        if (kt + 1 < NKT) STAGE1((kt + 1) * BK, cur ^ 1);

        s16x8 af[4], bfr[4];
#pragma unroll
        for (int mi = 0; mi < 4; ++mi)
            af[mi] = *(const s16x8*)&As[cur][(wr + mi * 16 + lr) * BK + ((lg ^ lswz) * 8)];
#pragma unroll
        for (int ni = 0; ni < 4; ++ni)
            bfr[ni] = *(const s16x8*)&Bs[cur][(wc + ni * 16 + lr) * BK + ((lg ^ lswz) * 8)];
        __builtin_amdgcn_s_setprio(1);
#pragma unroll
        for (int mi = 0; mi < 4; ++mi)
#pragma unroll
            for (int ni = 0; ni < 4; ++ni)
                acc[mi][ni] = __builtin_amdgcn_mfma_f32_16x16x32_bf16(af[mi], bfr[ni],
                                                                      acc[mi][ni], 0, 0, 0);
        __builtin_amdgcn_s_setprio(0);
        __syncthreads();  // one barrier per iter
    }
#undef STAGE1

    const int rb = brow + wr + lg * 4;
    const int cb = bcol + wc + lr;

    float bv[4], wv[4];
#pragma unroll
    for (int ni = 0; ni < 4; ++ni) {
        bv[ni] = bias[cb + ni * 16];
        wv[ni] = w2a[cb + ni * 16];
    }
#pragma unroll
    for (int mi = 0; mi < 4; ++mi) {
#pragma unroll
        for (int rr = 0; rr < 4; ++rr) {
            float sum = 0.f;
#pragma unroll
            for (int ni = 0; ni < 4; ++ni) {
                float v = fmaxf(acc[mi][ni][rr] + bv[ni], 0.0f);
                sum += v * wv[ni];
            }
#pragma unroll
            for (int off = 1; off < 16; off <<= 1) sum += __shfl_xor(sum, off, 64);
            int row = rb + mi * 16 + rr;
            if (lr == 0 && row < N_NODES_C) atomicAdd(&s_out[row], sum);
        }
    }
}

// ---------------- launch ----------------

extern "C" void kernel_launch(void* const* d_in, const int* in_sizes, int n_in,
                              void* d_out, int out_size, void* d_ws, size_t ws_size,
                              hipStream_t stream) {
    const float* x     = (const float*)d_in[0];
    const int*   ei    = (const int*)d_in[1];
    const int*   batch = (const int*)d_in[2];
    const float* W1a   = (const float*)d_in[3];
    const float* b1a   = (const float*)d_in[4];
    const float* W1b   = (const float*)d_in[5];
    const float* b1b   = (const float*)d_in[6];
    const float* W2a   = (const float*)d_in[7];
    const float* b2a   = (const float*)d_in[8];
    const float* W2b   = (const float*)d_in[9];
    const float* b2b   = (const float*)d_in[10];
    float* out = (float*)d_out;

    char* w = (char*)d_ws;
    short* z1   = (short*)(w);                  // 102,400,000
    short* y    = (short*)(w + 102400000);      // 102,400,000
    short* WT1  = (short*)(w + 204800000);      // 524,288
    short* WT2  = (short*)(w + 205324288);      // 524,288
    float* sbuf = (float*)(w + 205848576);      // 400,000
    float* aggs = (float*)(w + 206248576);      // 400,000
    int*   cnt  = (int*)  (w + 206648576);      // 400,000
    int*   offb = (int*)  (w + 207048576);      // 400,000
    int*   ssrc = (int*)  (w + 207448576);      // 600,000
    int*   bsum = (int*)  (w + 208048576);      // 512
    float* gsum = (float*)(w + 208049088);      // 256
    float* gcnt = (float*)(w + 208049344);      // 256

    // sbuf+aggs+cnt are contiguous (1.2 MB), gsum+gcnt contiguous (512 B)
    hipMemsetAsync(sbuf, 0, 1200000, stream);
    hipMemsetAsync(gsum, 0, 512, stream);
    transpose_w2<<<dim3(16, 16, 2), 256, 0, stream>>>(W1a, W1b, WT1, WT2);

    // CSR build (independent of GEMM0)
    hist_k<<<586, 256, 0, stream>>>(ei, cnt);
    scan1_k<<<NSCAN_BLK, 1024, 0, stream>>>(cnt, offb, bsum);
    scan2_k<<<1, 128, 0, stream>>>(bsum);
    scan3_k<<<NSCAN_BLK, 1024, 0, stream>>>(offb, bsum);
    place_k<<<586, 256, 0, stream>>>(ei, offb, ssrc);

    // y = bf16(x) @ W1a  (f32 A, fused convert in staging)
    gemm0_k<<<NWG, 256, 0, stream>>>(x, WT1, y);
    // z1 = relu(y + agg(y) + b1a)
    gather_relu_k<<<25000, 256, 0, stream>>>(y, offb, ssrc, b1a, z1);
    // s = relu(z1 @ W1b + b1b) . W2a
    gemm1_k<<<NWG, 256, 0, stream>>>(z1, WT2, b1b, W2a, sbuf);

    edge_scalar<<<586, 256, 0, stream>>>(ei, sbuf, aggs);
    node_pool<<<391, 256, 0, stream>>>(sbuf, aggs, batch, b2a, gsum, gcnt);
    finalize_k<<<1, 64, 0, stream>>>(gsum, gcnt, W2b, b2b, out);
}